// Round 1
// baseline (341.553 us; speedup 1.0000x reference)
//
#include <hip/hip_runtime.h>

// Problem constants
#define BATCH 512
#define TT    256   // seq len == block_size
#define CC    384   // n_embd
#define HH    64    // head size
// Fused GEMM: [256 x 384] @ [384 x 320] where cols 0..255 = S (scores), 256..319 = V
#define NCOL  320

typedef float  f32x4 __attribute__((ext_vector_type(4)));
typedef short  s16x8 __attribute__((ext_vector_type(8)));

// LDS map (bytes)
#define X_OFF   0        // X chunk, frag-ordered: 16 row-tiles * 64 lanes * 16B = 16384
#define W_OFF   16384    // W chunk: 20 col-tiles * 64 * 16B = 20480
#define P_OFF   36864    // packed triangular E blob: 72 tiles * 1024B = 73728
#define V_OFF   110592   // V blob (B^T frag order): 4 ct * 8 kc * 64 * 16B = 32768
#define RS_OFF  143360   // rowsum2: 2 * 256 floats = 2048
#define LDS_TOTAL 145408

__device__ __forceinline__ unsigned short f2bf(float f) {
    union { float f; unsigned u; } c; c.f = f;
    unsigned u = c.u;
    u += 0x7fffu + ((u >> 16) & 1u);   // RNE
    return (unsigned short)(u >> 16);
}

// prefix(rt) = number of packed 16x32 P-tiles before row-tile rt; ntiles(rt) = rt/2 + 1
__device__ __forceinline__ int prefix_of(int rt) {
    int a = rt >> 1, bb = rt & 1;
    return rt + a * (a - 1) + bb * a;
}

// ---------------- Kernel A: build bf16 weight blob in ws ----------------
// Blob layout: [kc(12)][ct(20)][lane(64)][8 bf16]; element (k in [0,384), n in [0,320)):
//   kc = k>>5, ct = n>>4, lane = ((k>>3)&3)*16 + (n&15), j = k&7
// ct 0..15 = W_s^T = (W_q@W_ql + W_k@W_kl)^T, ct 16..19 = W_v^T.
__global__ void prep_w(const float* __restrict__ Wq, const float* __restrict__ Wk,
                       const float* __restrict__ Wv, const float* __restrict__ Wql,
                       const float* __restrict__ Wkl, unsigned short* __restrict__ wsW) {
    int gid = blockIdx.x * 256 + threadIdx.x;   // grid covers exactly 384*256 + 384*64
    int k, n; float val;
    if (gid < CC * 256) {
        k = gid >> 8; int s = gid & 255; n = s;
        float acc = 0.f;
        for (int h = 0; h < HH; ++h)
            acc += Wq[k * HH + h] * Wql[h * 256 + s] + Wk[k * HH + h] * Wkl[h * 256 + s];
        val = acc;
    } else {
        int g2 = gid - CC * 256;
        k = g2 >> 6; int h = g2 & 63; n = 256 + h;
        val = Wv[k * HH + h];
    }
    int kc = k >> 5, ct = n >> 4;
    int lane = ((k >> 3) & 3) * 16 + (n & 15);
    int j = k & 7;
    wsW[(((kc * 20 + ct) * 64) + lane) * 8 + j] = f2bf(val);
}

// ---------------- Kernel B: per-batch fused attention ----------------
__global__ __launch_bounds__(512) void head_main(const float* __restrict__ x,
                                                 const unsigned short* __restrict__ wsW,
                                                 float* __restrict__ out) {
    extern __shared__ char sm[];
    unsigned short* Xs = (unsigned short*)(sm + X_OFF);
    unsigned short* Ws = (unsigned short*)(sm + W_OFF);
    unsigned short* Pb = (unsigned short*)(sm + P_OFF);
    unsigned short* Vb = (unsigned short*)(sm + V_OFF);
    float*          rs = (float*)(sm + RS_OFF);

    const int b    = blockIdx.x;
    const int t    = threadIdx.x;
    const int w    = t >> 6;          // wave 0..7
    const int lane = t & 63;
    const int cgrp = w >> 2;          // 0: cols 0..159, 1: cols 160..319
    const int iw   = w & 3;
    const int q    = lane >> 4;       // quad
    const int cidx = lane & 15;
    // Balanced causal row-tile assignment: each wave gets a low/high mix.
    const int rts[4] = { iw, 7 - iw, 8 + iw, 15 - iw };
    const int rtmax  = 15 - iw;

    f32x4 acc[4][10];
#pragma unroll
    for (int a = 0; a < 4; ++a)
#pragma unroll
        for (int c2 = 0; c2 < 10; ++c2) acc[a][c2] = (f32x4){0.f, 0.f, 0.f, 0.f};

    const float* xb = x + (size_t)b * (TT * CC);

    // ---- Phase 1: [S|V] = X @ [Ws|Wv], K-loop over 12 chunks of 32 ----
    for (int kc = 0; kc < 12; ++kc) {
        __syncthreads();
        // stage X chunk (fp32 -> bf16, A-frag order): 1024 slots of 16B
#pragma unroll
        for (int ssi = 0; ssi < 2; ++ssi) {
            int slot = t + ssi * 512;
            int rt = slot >> 6, L = slot & 63;
            int row  = rt * 16 + (L & 15);
            int koff = (L >> 4) * 8;
            const float4* src = (const float4*)(xb + row * CC + kc * 32 + koff);
            float4 f0 = src[0], f1 = src[1];
            s16x8 v;
            v[0] = (short)f2bf(f0.x); v[1] = (short)f2bf(f0.y);
            v[2] = (short)f2bf(f0.z); v[3] = (short)f2bf(f0.w);
            v[4] = (short)f2bf(f1.x); v[5] = (short)f2bf(f1.y);
            v[6] = (short)f2bf(f1.z); v[7] = (short)f2bf(f1.w);
            *(s16x8*)(Xs + slot * 8) = v;
        }
        // stage W chunk (already bf16 frag order in ws): 1280 x 16B
        {
            const float4* src = (const float4*)(wsW + (size_t)kc * (20 * 64 * 8));
            float4* dst = (float4*)Ws;
            dst[t]        = src[t];
            dst[t + 512]  = src[t + 512];
            if (t < 256) dst[t + 1024] = src[t + 1024];
        }
        __syncthreads();

        s16x8 af[4];
#pragma unroll
        for (int ri = 0; ri < 4; ++ri)
            af[ri] = *(const s16x8*)(Xs + (rts[ri] * 64 + lane) * 8);
#pragma unroll
        for (int cc2 = 0; cc2 < 10; ++cc2) {
            int ctg = cgrp * 10 + cc2;
            if (ctg <= 15 && ctg > rtmax) continue;  // S tile fully above diagonal for all our rows
            s16x8 bf = *(const s16x8*)(Ws + (ctg * 64 + lane) * 8);
#pragma unroll
            for (int ri = 0; ri < 4; ++ri) {
                if (ctg >= 16 || ctg <= rts[ri])
                    acc[ri][cc2] = __builtin_amdgcn_mfma_f32_16x16x32_bf16(af[ri], bf, acc[ri][cc2], 0, 0, 0);
            }
        }
    }

    // ---- Phase 1 epilogue: E = exp(tanh(S)) masked -> Pb; V -> Vb; row sums ----
    float rsum[4][4];
#pragma unroll
    for (int ri = 0; ri < 4; ++ri)
#pragma unroll
        for (int rg = 0; rg < 4; ++rg) rsum[ri][rg] = 0.f;

#pragma unroll
    for (int ri = 0; ri < 4; ++ri) {
        int rt = rts[ri];
#pragma unroll
        for (int cc2 = 0; cc2 < 10; ++cc2) {
            int ctg = cgrp * 10 + cc2;
            if (ctg >= 16) continue;
            if ((ctg >> 1) > (rt >> 1)) continue;        // tile not stored in packed blob
            int tix = prefix_of(rt) + (ctg >> 1);
#pragma unroll
            for (int rg = 0; rg < 4; ++rg) {
                int row = rt * 16 + q * 4 + rg;          // C layout: row = quad*4 + reg
                int col = ctg * 16 + cidx;               // col = lane&15
                float e = 0.f;
                if (col <= row) {
                    float sv = acc[ri][cc2][rg];
                    float ex = __expf(2.f * sv);
                    float th = 1.f - 2.f / (ex + 1.f);   // tanh
                    e = __expf(th);                      // unnormalized softmax (tanh bounded -> safe)
                }
                rsum[ri][rg] += e;
                int sl = col & 31;
                Pb[(tix * 64 + (sl >> 3) * 16 + (row & 15)) * 8 + (sl & 7)] = f2bf(e);
            }
        }
        if (cgrp == 1) {   // V tiles: ctg 16..19 -> B^T frag order blob
#pragma unroll
            for (int cc2 = 6; cc2 < 10; ++cc2) {
                int vct = cc2 - 6;
#pragma unroll
                for (int rg = 0; rg < 4; ++rg) {
                    int srow = rt * 16 + q * 4 + rg;     // k index of PV
                    int kcv = srow >> 5;
                    Vb[((vct * 8 + kcv) * 64 + ((srow >> 3) & 3) * 16 + cidx) * 8 + (srow & 7)] =
                        f2bf(acc[ri][cc2][rg]);
                }
            }
        }
        // per-row partial sums: reduce across the 16 lanes of each quad
#pragma unroll
        for (int rg = 0; rg < 4; ++rg) {
            float v = rsum[ri][rg];
            v += __shfl_xor(v, 1);
            v += __shfl_xor(v, 2);
            v += __shfl_xor(v, 4);
            v += __shfl_xor(v, 8);
            if (cidx == 0) rs[cgrp * 256 + rt * 16 + q * 4 + rg] = v;
        }
    }
    __syncthreads();

    // ---- Phase 2: out = (E @ V) / rowsum ----
    const int r2s[2] = { w, 15 - w };
    f32x4 acc2[2][4];
#pragma unroll
    for (int r2 = 0; r2 < 2; ++r2)
#pragma unroll
        for (int ct = 0; ct < 4; ++ct) acc2[r2][ct] = (f32x4){0.f, 0.f, 0.f, 0.f};

    const int kcmax = (15 - w) >> 1;
    for (int kc = 0; kc <= kcmax; ++kc) {
        s16x8 vb[4];
#pragma unroll
        for (int ct = 0; ct < 4; ++ct)
            vb[ct] = *(const s16x8*)(Vb + ((ct * 8 + kc) * 64 + lane) * 8);
#pragma unroll
        for (int r2 = 0; r2 < 2; ++r2) {
            int rt = r2s[r2];
            if (kc <= (rt >> 1)) {
                s16x8 pf = *(const s16x8*)(Pb + ((prefix_of(rt) + kc) * 64 + lane) * 8);
#pragma unroll
                for (int ct = 0; ct < 4; ++ct)
                    acc2[r2][ct] = __builtin_amdgcn_mfma_f32_16x16x32_bf16(pf, vb[ct], acc2[r2][ct], 0, 0, 0);
            }
        }
    }

    float* ob = out + (size_t)b * (TT * HH);
#pragma unroll
    for (int r2 = 0; r2 < 2; ++r2) {
        int rt = r2s[r2];
#pragma unroll
        for (int rg = 0; rg < 4; ++rg) {
            int row = rt * 16 + q * 4 + rg;
            float inv = 1.f / (rs[row] + rs[256 + row]);
#pragma unroll
            for (int ct = 0; ct < 4; ++ct)
                ob[row * HH + ct * 16 + cidx] = acc2[r2][ct][rg] * inv;
        }
    }
}

extern "C" void kernel_launch(void* const* d_in, const int* in_sizes, int n_in,
                              void* d_out, int out_size, void* d_ws, size_t ws_size,
                              hipStream_t stream) {
    const float* x   = (const float*)d_in[0];
    const float* Wq  = (const float*)d_in[1];
    const float* Wk  = (const float*)d_in[2];
    const float* Wv  = (const float*)d_in[3];
    const float* Wql = (const float*)d_in[4];
    const float* Wkl = (const float*)d_in[5];
    unsigned short* wsW = (unsigned short*)d_ws;   // 245760 B blob
    float* out = (float*)d_out;

    prep_w<<<480, 256, 0, stream>>>(Wq, Wk, Wv, Wql, Wkl, wsW);

    // 142 KB dynamic LDS needs the opt-in (gfx950 has 160 KB/CU). Same call every
    // launch (no static guards); host-side attr set is graph-capture safe.
    hipFuncSetAttribute((const void*)head_main,
                        hipFuncAttributeMaxDynamicSharedMemorySize, LDS_TOTAL);
    head_main<<<BATCH, 512, LDS_TOTAL, stream>>>(x, wsW, out);
}

// Round 2
// 320.986 us; speedup vs baseline: 1.0641x; 1.0641x over previous
//
#include <hip/hip_runtime.h>

// Problem: B=512, T=256, C=384, HS=64.  out = softmax(tril(tanh(x@Ws))) @ (x@Wv)
// with Ws = Wq@Wql + Wk@Wkl  (elementwise add of q_w,k_w collapses: both linear in x).
#define BATCH 512
#define TT    256
#define CC    384
#define HH    64

typedef float  f32x4 __attribute__((ext_vector_type(4)));
typedef short  s16x8 __attribute__((ext_vector_type(8)));

// LDS map (bytes)
#define XS_OFF   0        // X chunk  [kk2][rt16][lane64][8] bf16 = 32768
#define WS_OFF   32768    // W chunks [buf2][kk2][ct20][lane64][8] bf16 = 81920
#define VB_OFF   114688   // V blob (B-frag order) [vct4][kc8][lane64][8] bf16 = 32768
#define SCR_OFF  147456   // per-wave P-transpose scratch, 8 x 1024B
#define LDS_TOTAL 155648

__device__ __forceinline__ unsigned short f2bf(float f) {
    union { float f; unsigned u; } c; c.f = f;
    unsigned u = c.u;
    u += 0x7fffu + ((u >> 16) & 1u);   // RNE
    return (unsigned short)(u >> 16);
}

// async global->LDS, 16B per lane. HW: wave-uniform base + lane*16 — our dst is
// lane-linear by construction. Casts go through integers (generic->AS3 = low 32 bits).
__device__ __forceinline__ void gld_lds16(const void* g, void* l) {
    __builtin_amdgcn_global_load_lds(
        (const __attribute__((address_space(1))) unsigned int*)(unsigned long long)g,
        (__attribute__((address_space(3))) unsigned int*)(unsigned int)(unsigned long long)l,
        16, 0, 0);
}

// ---------------- Kernel A: build bf16 weight blob in ws ----------------
// Blob: [kc6][kk2][ct20][lane64][j8] bf16.  Element (k in [0,384), n in [0,320)):
//   kc=k>>6, kk=(k>>5)&1, ct=n>>4, lane=((k>>3)&3)*16 + (n&15), j=k&7.
// ct 0..15 = Ws^T (B-frag), ct 16..19 = Wv^T.
__global__ void prep_w(const float* __restrict__ Wq, const float* __restrict__ Wk,
                       const float* __restrict__ Wv, const float* __restrict__ Wql,
                       const float* __restrict__ Wkl, unsigned short* __restrict__ wsW) {
    int gid = blockIdx.x * 256 + threadIdx.x;   // covers 384*256 + 384*64 = 122880
    int k, n; float val;
    if (gid < CC * 256) {
        k = gid >> 8; int s = gid & 255; n = s;
        float acc = 0.f;
        for (int h = 0; h < HH; ++h)
            acc += Wq[k * HH + h] * Wql[h * 256 + s] + Wk[k * HH + h] * Wkl[h * 256 + s];
        val = acc;
    } else {
        int g2 = gid - CC * 256;
        k = g2 >> 6; int h = g2 & 63; n = 256 + h;
        val = Wv[k * HH + h];
    }
    int kc = k >> 6, kk = (k >> 5) & 1, ct = n >> 4;
    int lane = ((k >> 3) & 3) * 16 + (n & 15);
    int j = k & 7;
    wsW[((((kc * 2 + kk) * 20 + ct) * 64) + lane) * 8 + j] = f2bf(val);
}

// ---------------- Kernel B: per-batch fused attention ----------------
__global__ __launch_bounds__(512, 2) void head_main(const float* __restrict__ x,
                                                    const unsigned short* __restrict__ wsW,
                                                    float* __restrict__ out) {
    extern __shared__ char sm[];
    unsigned short* Xs  = (unsigned short*)(sm + XS_OFF);
    unsigned short* Wsh = (unsigned short*)(sm + WS_OFF);
    unsigned short* Vb  = (unsigned short*)(sm + VB_OFF);

    const int b    = blockIdx.x;
    const int t    = threadIdx.x;
    const int w    = (t >> 6) & 7;      // wave 0..7 (&7 so compiler knows range)
    const int lane = t & 63;
    const int q    = lane >> 4;
    const int cidx = lane & 15;
    const int rt0  = w;                 // <= 7
    const int rt1  = 15 - w;            // >= 8
    unsigned short* scr = (unsigned short*)(sm + SCR_OFF) + w * 512;  // 1KB/wave

    const float* xb = x + (size_t)b * (TT * CC);

    // Accumulators: wave owns row-tiles rt0,rt1 across ALL col-tiles (causal-trimmed).
    f32x4 accS0[8], accS1[16], accV[2][4];
#pragma unroll
    for (int i = 0; i < 8; ++i)  accS0[i] = (f32x4){0.f,0.f,0.f,0.f};
#pragma unroll
    for (int i = 0; i < 16; ++i) accS1[i] = (f32x4){0.f,0.f,0.f,0.f};
#pragma unroll
    for (int i = 0; i < 2; ++i)
#pragma unroll
        for (int j = 0; j < 4; ++j) accV[i][j] = (f32x4){0.f,0.f,0.f,0.f};

    // X prefetch address precompute: granule g = t + i*512 of [kk2][rt16][lane64] (16B)
    int xrow[4], xkoff[4];
#pragma unroll
    for (int i = 0; i < 4; ++i) {
        int g = t + i * 512;
        int kk = g >> 10, rt = (g >> 6) & 15, L = g & 63;
        xrow[i]  = rt * 16 + (L & 15);
        xkoff[i] = kk * 32 + ((L >> 4) & 3) * 8;
    }

    // ---- prologue: prefetch chunk 0 (X -> regs, W -> LDS buf0 async) ----
    float4 xf[8];
#pragma unroll
    for (int i = 0; i < 4; ++i) {
        const float4* p = (const float4*)(xb + xrow[i] * CC + xkoff[i]);
        xf[2*i]   = p[0];
        xf[2*i+1] = p[1];
    }
#pragma unroll
    for (int i = 0; i < 5; ++i) {
        int g = t + i * 512;
        gld_lds16(wsW + g * 8, Wsh + g * 8);
    }

    // ---- K-loop: 6 iterations of BK=64, 1-deep pipeline ----
    for (int kc = 0; kc < 6; ++kc) {
        // store prefetched X (convert fp32->bf16) into Xs
#pragma unroll
        for (int i = 0; i < 4; ++i) {
            int g = t + i * 512;
            float4 f0 = xf[2*i], f1 = xf[2*i+1];
            s16x8 v;
            v[0] = (short)f2bf(f0.x); v[1] = (short)f2bf(f0.y);
            v[2] = (short)f2bf(f0.z); v[3] = (short)f2bf(f0.w);
            v[4] = (short)f2bf(f1.x); v[5] = (short)f2bf(f1.y);
            v[6] = (short)f2bf(f1.z); v[7] = (short)f2bf(f1.w);
            *(s16x8*)(Xs + g * 8) = v;
        }
        __syncthreads();   // barrier1: Xs visible; W(kc) arrived (vmcnt drained here/earlier)

        // issue NEXT chunk's loads now — they overlap all of compute below
        if (kc < 5) {
            const int kn = kc + 1;
#pragma unroll
            for (int i = 0; i < 4; ++i) {
                const float4* p = (const float4*)(xb + xrow[i] * CC + kn * 64 + xkoff[i]);
                xf[2*i]   = p[0];
                xf[2*i+1] = p[1];
            }
            const unsigned short* wsrc = wsW + (size_t)kn * 20480;
            unsigned short*       wdst = Wsh + (kn & 1) * 20480;
#pragma unroll
            for (int i = 0; i < 5; ++i) {
                int g = t + i * 512;
                gld_lds16(wsrc + g * 8, wdst + g * 8);
            }
        }

        // compute chunk kc
        const unsigned short* Wb = Wsh + (kc & 1) * 20480;
#pragma unroll
        for (int kk = 0; kk < 2; ++kk) {
            s16x8 a0 = *(const s16x8*)(Xs + ((kk * 16 + rt0) * 64 + lane) * 8);
            s16x8 a1 = *(const s16x8*)(Xs + ((kk * 16 + rt1) * 64 + lane) * 8);
#pragma unroll
            for (int ct = 0; ct < 16; ++ct) {
                if (ct <= rt1) {           // rt1 >= 8: folds true for ct<=8
                    s16x8 bf = *(const s16x8*)(Wb + ((kk * 20 + ct) * 64 + lane) * 8);
                    accS1[ct] = __builtin_amdgcn_mfma_f32_16x16x32_bf16(a1, bf, accS1[ct], 0, 0, 0);
                    if (ct < 8 && ct <= rt0)
                        accS0[ct] = __builtin_amdgcn_mfma_f32_16x16x32_bf16(a0, bf, accS0[ct], 0, 0, 0);
                }
            }
#pragma unroll
            for (int v2 = 0; v2 < 4; ++v2) {
                s16x8 bf = *(const s16x8*)(Wb + ((kk * 20 + 16 + v2) * 64 + lane) * 8);
                accV[0][v2] = __builtin_amdgcn_mfma_f32_16x16x32_bf16(a0, bf, accV[0][v2], 0, 0, 0);
                accV[1][v2] = __builtin_amdgcn_mfma_f32_16x16x32_bf16(a1, bf, accV[1][v2], 0, 0, 0);
            }
        }
        __syncthreads();   // barrier2: compute done; drains next chunk's loads (HBM busy during compute)
    }

    // ---- epilogue: E = exp(tanh(S)) masked -> A-frags (via per-wave scratch), V -> Vb, rowsums ----
    float rs0[4] = {0.f,0.f,0.f,0.f}, rs1[4] = {0.f,0.f,0.f,0.f};
    s16x8 pf0[4], pf1[8];

#pragma unroll
    for (int ch = 0; ch < 8; ++ch) {
        if (ch <= (rt1 >> 1)) {
#pragma unroll
            for (int sub = 0; sub < 2; ++sub) {
                const int ct = 2 * ch + sub;
                const int gcol = ct * 16 + cidx;
                const int c = sub * 16 + cidx;
#pragma unroll
                for (int rg = 0; rg < 4; ++rg) {
                    const int grow = rt1 * 16 + q * 4 + rg;
                    float e = 0.f;
                    if (ct <= rt1 && gcol <= grow) {
                        float sv = accS1[2 * ch + sub][rg];
                        float ex = __expf(2.f * sv);
                        float th = 1.f - __fdividef(2.f, ex + 1.f);   // tanh
                        e = __expf(th);                                // bounded -> no max-sub needed
                    }
                    rs1[rg] += e;
                    scr[((c >> 3) * 16 + q * 4 + rg) * 8 + (c & 7)] = f2bf(e);
                }
            }
            pf1[ch] = *(const s16x8*)(scr + lane * 8);   // in-wave DS ordered
        }
    }
#pragma unroll
    for (int ch = 0; ch < 4; ++ch) {
        if (ch <= (rt0 >> 1)) {
#pragma unroll
            for (int sub = 0; sub < 2; ++sub) {
                const int ct = 2 * ch + sub;
                const int gcol = ct * 16 + cidx;
                const int c = sub * 16 + cidx;
#pragma unroll
                for (int rg = 0; rg < 4; ++rg) {
                    const int grow = rt0 * 16 + q * 4 + rg;
                    float e = 0.f;
                    if (ct <= rt0 && gcol <= grow) {
                        float sv = accS0[2 * ch + sub][rg];
                        float ex = __expf(2.f * sv);
                        float th = 1.f - __fdividef(2.f, ex + 1.f);
                        e = __expf(th);
                    }
                    rs0[rg] += e;
                    scr[((c >> 3) * 16 + q * 4 + rg) * 8 + (c & 7)] = f2bf(e);
                }
            }
            pf0[ch] = *(const s16x8*)(scr + lane * 8);
        }
    }

    // V -> Vb (B-frag order for PV)
#pragma unroll
    for (int ri = 0; ri < 2; ++ri) {
        const int rt = ri ? rt1 : rt0;
#pragma unroll
        for (int vct = 0; vct < 4; ++vct)
#pragma unroll
            for (int rg = 0; rg < 4; ++rg) {
                int srow = rt * 16 + q * 4 + rg;
                Vb[((vct * 8 + (srow >> 5)) * 64 + ((srow >> 3) & 3) * 16 + cidx) * 8 + (srow & 7)] =
                    f2bf(accV[ri][vct][rg]);
            }
    }

    // rowsums: reduce across the 16 lanes sharing each row (quad-group), replicated
#pragma unroll
    for (int rg = 0; rg < 4; ++rg) {
        float v0 = rs0[rg], v1 = rs1[rg];
        v0 += __shfl_xor(v0, 1); v0 += __shfl_xor(v0, 2);
        v0 += __shfl_xor(v0, 4); v0 += __shfl_xor(v0, 8);
        v1 += __shfl_xor(v1, 1); v1 += __shfl_xor(v1, 2);
        v1 += __shfl_xor(v1, 4); v1 += __shfl_xor(v1, 8);
        rs0[rg] = v0; rs1[rg] = v1;
    }

    __syncthreads();   // Vb visible to all waves

    // ---- phase 2: out = (E @ V) / rowsum — fully per-wave ----
    f32x4 acc2[2][4];
#pragma unroll
    for (int i = 0; i < 2; ++i)
#pragma unroll
        for (int j = 0; j < 4; ++j) acc2[i][j] = (f32x4){0.f,0.f,0.f,0.f};

    const int nch0 = rt0 >> 1, nch1 = rt1 >> 1;
#pragma unroll
    for (int ch = 0; ch < 8; ++ch) {
        if (ch <= nch1) {
            s16x8 vb[4];
#pragma unroll
            for (int vct = 0; vct < 4; ++vct)
                vb[vct] = *(const s16x8*)(Vb + ((vct * 8 + ch) * 64 + lane) * 8);
#pragma unroll
            for (int vct = 0; vct < 4; ++vct)
                acc2[1][vct] = __builtin_amdgcn_mfma_f32_16x16x32_bf16(pf1[ch], vb[vct], acc2[1][vct], 0, 0, 0);
            if (ch < 4 && ch <= nch0) {
#pragma unroll
                for (int vct = 0; vct < 4; ++vct)
                    acc2[0][vct] = __builtin_amdgcn_mfma_f32_16x16x32_bf16(pf0[ch], vb[vct], acc2[0][vct], 0, 0, 0);
            }
        }
    }

    float* ob = out + (size_t)b * (TT * HH);
#pragma unroll
    for (int ri = 0; ri < 2; ++ri) {
        const int rt = ri ? rt1 : rt0;
#pragma unroll
        for (int rg = 0; rg < 4; ++rg) {
            int row = rt * 16 + q * 4 + rg;
            float inv = __fdividef(1.f, ri ? rs1[rg] : rs0[rg]);
#pragma unroll
            for (int vct = 0; vct < 4; ++vct)
                ob[row * HH + vct * 16 + cidx] = acc2[ri][vct][rg] * inv;
        }
    }
}

extern "C" void kernel_launch(void* const* d_in, const int* in_sizes, int n_in,
                              void* d_out, int out_size, void* d_ws, size_t ws_size,
                              hipStream_t stream) {
    const float* x   = (const float*)d_in[0];
    const float* Wq  = (const float*)d_in[1];
    const float* Wk  = (const float*)d_in[2];
    const float* Wv  = (const float*)d_in[3];
    const float* Wql = (const float*)d_in[4];
    const float* Wkl = (const float*)d_in[5];
    unsigned short* wsW = (unsigned short*)d_ws;   // 245760 B blob
    float* out = (float*)d_out;

    prep_w<<<480, 256, 0, stream>>>(Wq, Wk, Wv, Wql, Wkl, wsW);

    hipFuncSetAttribute((const void*)head_main,
                        hipFuncAttributeMaxDynamicSharedMemorySize, LDS_TOTAL);
    head_main<<<BATCH, 512, LDS_TOTAL, stream>>>(x, wsW, out);
}